// Round 9
// baseline (4252.119 us; speedup 1.0000x reference)
//
#include <hip/hip_runtime.h>
#include <hip/hip_bf16.h>

// LSTM trajectory predictor, Round 9: counted-vmcnt pipeline.
// A (h-state): 3 LDS buffers, staged 2 chunks ahead. B (weights): 2 buffers,
// staged 1 ahead. Per chunk: s_waitcnt vmcnt(4) (never 0 in the loop) +
// raw s_barrier. 80KB LDS/block -> 2 blocks/CU. Paired dispatches kept.

#define HDIM 512
#define BDIM 2048
#define T_HIST 50
#define T_FUT 30

typedef __attribute__((ext_vector_type(8))) short short8;
typedef __attribute__((ext_vector_type(4))) float f32x4;

#define AS1(p) ((const __attribute__((address_space(1))) void*)(p))
#define AS3(p) ((__attribute__((address_space(3))) void*)(p))

__device__ __forceinline__ ushort f2bf(float f) {
    union { float f; unsigned u; } v; v.f = f;
    unsigned r = v.u + 0x7fff + ((v.u >> 16) & 1);   // RNE
    return (ushort)(r >> 16);
}
__device__ __forceinline__ float bf2f(ushort h) {
    union { unsigned u; float f; } v; v.u = ((unsigned)h) << 16;
    return v.f;
}

// Region layout (128 rows x 32 k, 16B slots, 4 slots/row):
// q = row>>1, t = ((row&1)<<2)|slot, phys = q*8 + (t ^ (q&7)).  Bijective;
// frag reads (16 rows x 4 slots) hit all 32 banks conflict-free.
__device__ __forceinline__ int swz(int row, int slot) {
    int q = row >> 1;
    int t = ((row & 1) << 2) | slot;
    return q * 8 + (t ^ (q & 7));
}

// ---- weight prep: fp32 [2048][512] -> bf16 hi/lo, rows permuted so a
// block's 128 rows = 32 units x 4 gates.
// input row = g*512 + u ; rp = (u>>5)*128 + ((u>>4)&1)*64 + g*16 + (u&15)
struct SplitSrc { const float* src[6]; };

__global__ __launch_bounds__(256) void split_weights(SplitSrc s, ushort* __restrict__ hi,
                                                     ushort* __restrict__ lo) {
    int row = blockIdx.x;             // g*512 + u
    int j = blockIdx.y;               // matrix index
    int g = row >> 9, u = row & 511;
    int rp = (u >> 5) * 128 + ((u >> 4) & 1) * 64 + g * 16 + (u & 15);
    const float* S = s.src[j] + (size_t)row * HDIM;
    ushort* H = hi + ((size_t)j * 2048 + rp) * HDIM;
    ushort* L = lo + ((size_t)j * 2048 + rp) * HDIM;
    for (int k = threadIdx.x; k < HDIM; k += 256) {
        float w = S[k];
        ushort hb = f2bf(w);
        H[k] = hb;
        L[k] = f2bf(w - bf2f(hb));
    }
}

// ---- cell descriptor ----
struct CellDesc {
    const ushort *A1h, *A1l, *W1h, *W1l;
    const ushort *A2h, *A2l, *W2h, *W2l;
    const float *x; const float *Wx;           // encoder tiny-K input path
    const float *bih, *bhh;
    const ushort *hsrc_hi, *hsrc_lo;           // decoder: h1 for head-fold (HF)
    const float *Wout, *bout; float *out_t;    // head-fold params (HF)
    float* c; ushort *hh; ushort *hl;
    int np, xs, Kx;
};

// ---- fused LSTM cell(s): blocks [0,256) run dA, [256,512) run dB ----
// Block tile 128m x 128n (32 units x 4 gates), 4 waves 2x2, wave tile 64x64
// = 4 m-frags x 4 gate-frags of mfma_f32_16x16x32_bf16, 3-product split.
template <bool HF>
__global__ __launch_bounds__(256, 2) void lstm_cells(CellDesc dA, CellDesc dB) {
    // A buffers: 3 x 8192 ushorts (A_hi @+0, A_lo @+4096) = 48KB
    // B buffers: 2 x 8192 ushorts (B_hi @+0, B_lo @+4096) = 32KB  -> 80KB total
    __shared__ __align__(16) ushort lds[40960];

    const CellDesc d = (blockIdx.x >> 8) ? dB : dA;

    const int tid = threadIdx.x;
    const int w = tid >> 6, l = tid & 63;
    const int wm = w >> 1, wn = w & 1;
    const int lrow = l & 15, lk = l >> 4;

    // XCD-chunked bijective swizzle within each cell's 256 blocks
    int id = blockIdx.x & 255;
    int xcd = id & 7, rr = id >> 3;
    int bx = (xcd & 3) * 4 + (rr & 3);
    int by = (xcd >> 2) * 8 + (rr >> 2);
    const int m0 = by * 128;
    const int n0 = bx * 128;
    const int u  = bx * 32 + wn * 16 + lrow;   // global hidden unit

    f32x4 acc[4][4];   // [m-frag][gate]

    // lane's staging dest/source mapping (loop-invariant): 2 slots per lane
    // per region; dest slot db+l, source = inverse-swizzled logical address.
    int dbs[2]; size_t gos[2];
    #pragma unroll
    for (int it = 0; it < 2; ++it) {
        int db = (w * 2 + it) * 64;
        int dd = db + l;
        int q = dd >> 3, tp = dd & 7;
        int tl = tp ^ (q & 7);
        int r = (q << 1) | (tl >> 2);
        int s = tl & 3;
        dbs[it] = db;
        gos[it] = (size_t)r * HDIM + s * 8;
    }

    // ---- staging: A (hi+lo) for chunk t into A-buffer bufk ----
    auto STAGE_A = [&](int t, int bufk) {
        int p = t >> 4;
        int kc = (t & 15) * 32;
        const ushort* Ah = (p ? d.A2h : d.A1h) + (size_t)m0 * HDIM + kc;
        const ushort* Al = (p ? d.A2l : d.A1l) + (size_t)m0 * HDIM + kc;
        ushort* base = &lds[bufk * 8192];
        #pragma unroll
        for (int it = 0; it < 2; ++it) {
            __builtin_amdgcn_global_load_lds(AS1(Ah + gos[it]),
                                             AS3(base + dbs[it] * 8), 16, 0, 0);
            __builtin_amdgcn_global_load_lds(AS1(Al + gos[it]),
                                             AS3(base + 4096 + dbs[it] * 8), 16, 0, 0);
        }
    };
    // ---- staging: B (hi+lo) for chunk t into B-buffer t&1 ----
    auto STAGE_B = [&](int t) {
        int p = t >> 4;
        int kc = (t & 15) * 32;
        const ushort* Bh = (p ? d.W2h : d.W1h) + (size_t)n0 * HDIM + kc;
        const ushort* Bl = (p ? d.W2l : d.W1l) + (size_t)n0 * HDIM + kc;
        ushort* base = &lds[24576 + (t & 1) * 8192];
        #pragma unroll
        for (int it = 0; it < 2; ++it) {
            __builtin_amdgcn_global_load_lds(AS1(Bh + gos[it]),
                                             AS3(base + dbs[it] * 8), 16, 0, 0);
            __builtin_amdgcn_global_load_lds(AS1(Bl + gos[it]),
                                             AS3(base + 4096 + dbs[it] * 8), 16, 0, 0);
        }
    };

    const int nch = d.np * 16;
    // prologue: issue order matters for vmcnt counting (oldest first)
    STAGE_B(0);
    STAGE_A(0, 0);
    STAGE_A(1, 1);

    // ---- bias init ----
    #pragma unroll
    for (int g = 0; g < 4; ++g) {
        float b = d.bih[g * HDIM + u] + d.bhh[g * HDIM + u];
        f32x4 bv = {b, b, b, b};
        #pragma unroll
        for (int fm = 0; fm < 4; ++fm) acc[fm][g] = bv;
    }

    // ---- encoder tiny-K x path (K=5, reads history) ----
    if (d.Kx > 0) {
        for (int kx = 0; kx < d.Kx; ++kx) {
            float wv[4];
            #pragma unroll
            for (int g = 0; g < 4; ++g) wv[g] = d.Wx[(size_t)(g * HDIM + u) * d.Kx + kx];
            #pragma unroll
            for (int fm = 0; fm < 4; ++fm)
                #pragma unroll
                for (int r = 0; r < 4; ++r) {
                    int m = m0 + wm * 64 + fm * 16 + lk * 4 + r;
                    float xv = d.x[(size_t)m * d.xs + kx];
                    #pragma unroll
                    for (int g = 0; g < 4; ++g) acc[fm][g][r] += xv * wv[g];
                }
        }
    }

    // ---- decoder head-fold (HF only): x = h1_prev @ Wout^T + bout,
    // write out[t-1], then add x @ Wx^T into acc ----
    if constexpr (HF) {
        __shared__ float xlds[128][2];
        if (d.hsrc_hi) {
            int row = tid >> 1, half = tid & 1;
            const ushort* hh = d.hsrc_hi + (size_t)(m0 + row) * HDIM + half * 256;
            const ushort* hl = d.hsrc_lo + (size_t)(m0 + row) * HDIM + half * 256;
            float s0 = 0.f, s1 = 0.f;
            #pragma unroll 4
            for (int j = 0; j < 32; ++j) {
                short8 a = *(const short8*)(hh + j * 8);
                short8 b = *(const short8*)(hl + j * 8);
                #pragma unroll
                for (int e = 0; e < 8; ++e) {
                    float hv = bf2f((ushort)a[e]) + bf2f((ushort)b[e]);
                    int k = half * 256 + j * 8 + e;
                    s0 += hv * d.Wout[k];
                    s1 += hv * d.Wout[HDIM + k];
                }
            }
            s0 += __shfl_xor(s0, 1);
            s1 += __shfl_xor(s1, 1);
            float x0 = s0 + d.bout[0], x1 = s1 + d.bout[1];
            if (half == 0) {
                xlds[row][0] = x0; xlds[row][1] = x1;
                if (bx == 0 && d.out_t) {
                    d.out_t[(size_t)(m0 + row) * (T_FUT * 2) + 0] = x0;
                    d.out_t[(size_t)(m0 + row) * (T_FUT * 2) + 1] = x1;
                }
            }
            __syncthreads();
            #pragma unroll
            for (int g = 0; g < 4; ++g) {
                float w0 = d.Wx[(size_t)(g * HDIM + u) * 2 + 0];
                float w1 = d.Wx[(size_t)(g * HDIM + u) * 2 + 1];
                #pragma unroll
                for (int fm = 0; fm < 4; ++fm)
                    #pragma unroll
                    for (int r = 0; r < 4; ++r) {
                        int ml = wm * 64 + fm * 16 + lk * 4 + r;
                        acc[fm][g][r] += xlds[ml][0] * w0 + xlds[ml][1] * w1;
                    }
            }
        }
    }

    // ---- main loop: counted vmcnt keeps A(t+2) in flight across the barrier.
    // Pending order at top of iter t (oldest first): A(t+1), B(t+1)... wait
    // semantics: vmcnt(4) retires A(t) [if still pending], B(t), A(t+1)-older?
    // Issue order per iter: B(t+1) then A(t+2); so pending at top of t is
    // [A(t+1)@t-1, B(t)@t-1 ... ] -> vmcnt(4) leaves only A(t+2)'s 4 loads.
    int ca = 0;   // A buffer holding chunk t
    for (int t = 0; t < nch; ++t) {
        if (t + 1 < nch) {
            asm volatile("s_waitcnt vmcnt(4)" ::: "memory");
        } else {
            asm volatile("s_waitcnt vmcnt(0)" ::: "memory");
        }
        __builtin_amdgcn_s_barrier();    // chunk-t buffers published to block
        if (t + 1 < nch) STAGE_B(t + 1);
        if (t + 2 < nch) STAGE_A(t + 2, ca == 0 ? 2 : ca - 1);  // (ca+2)%3

        ushort* abase = &lds[ca * 8192];
        ushort* bbase = &lds[24576 + (t & 1) * 8192];
        short8 ah[4], al[4], bh[4], bl[4];
        #pragma unroll
        for (int fm = 0; fm < 4; ++fm) {
            int row = wm * 64 + fm * 16 + lrow;
            int off = swz(row, lk) * 8;
            ah[fm] = *(const short8*)(abase + off);
            al[fm] = *(const short8*)(abase + 4096 + off);
        }
        #pragma unroll
        for (int g = 0; g < 4; ++g) {
            int row = wn * 64 + g * 16 + lrow;
            int off = swz(row, lk) * 8;
            bh[g] = *(const short8*)(bbase + off);
            bl[g] = *(const short8*)(bbase + 4096 + off);
        }
        #pragma unroll
        for (int fm = 0; fm < 4; ++fm)
            #pragma unroll
            for (int g = 0; g < 4; ++g)
                acc[fm][g] = __builtin_amdgcn_mfma_f32_16x16x32_bf16(
                    ah[fm], bh[g], acc[fm][g], 0, 0, 0);
        #pragma unroll
        for (int fm = 0; fm < 4; ++fm)
            #pragma unroll
            for (int g = 0; g < 4; ++g)
                acc[fm][g] = __builtin_amdgcn_mfma_f32_16x16x32_bf16(
                    al[fm], bh[g], acc[fm][g], 0, 0, 0);
        #pragma unroll
        for (int fm = 0; fm < 4; ++fm)
            #pragma unroll
            for (int g = 0; g < 4; ++g)
                acc[fm][g] = __builtin_amdgcn_mfma_f32_16x16x32_bf16(
                    ah[fm], bl[g], acc[fm][g], 0, 0, 0);

        ca = (ca == 2) ? 0 : ca + 1;
    }

    // ---- epilogue: gates + state update. Thread owns 16 rows x 1 unit. ----
    #pragma unroll
    for (int fm = 0; fm < 4; ++fm)
        #pragma unroll
        for (int r = 0; r < 4; ++r) {
            int m = m0 + wm * 64 + fm * 16 + lk * 4 + r;
            size_t idx = (size_t)m * HDIM + u;
            float zi = acc[fm][0][r], zf = acc[fm][1][r];
            float zg = acc[fm][2][r], zo = acc[fm][3][r];
            float ig = 1.f / (1.f + __expf(-zi));
            float fg = 1.f / (1.f + __expf(-zf));
            float gg = 2.f / (1.f + __expf(-2.f * zg)) - 1.f;
            float og = 1.f / (1.f + __expf(-zo));
            float cn = fg * d.c[idx] + ig * gg;
            float hn = og * (2.f / (1.f + __expf(-2.f * cn)) - 1.f);
            d.c[idx] = cn;
            ushort hb = f2bf(hn);
            d.hh[idx] = hb;
            d.hl[idx] = f2bf(hn - bf2f(hb));
        }
}

// ---- final output for t=29 (no following D0 to fold into) ----
__global__ __launch_bounds__(256) void head_kernel(
    const ushort* __restrict__ hhi, const ushort* __restrict__ hlo,
    const float* __restrict__ Wout, const float* __restrict__ bout,
    float* __restrict__ out, int t)
{
    int wave = (blockIdx.x * 256 + threadIdx.x) >> 6;
    int lane = threadIdx.x & 63;
    const ushort* hr = hhi + (size_t)wave * HDIM;
    const ushort* lr = hlo + (size_t)wave * HDIM;
    float s0 = 0.f, s1 = 0.f;
    #pragma unroll
    for (int k = lane; k < HDIM; k += 64) {
        float hv = bf2f(hr[k]) + bf2f(lr[k]);
        s0 += hv * Wout[k];
        s1 += hv * Wout[HDIM + k];
    }
    #pragma unroll
    for (int off = 32; off > 0; off >>= 1) {
        s0 += __shfl_down(s0, off);
        s1 += __shfl_down(s1, off);
    }
    if (lane == 0) {
        out[(size_t)wave * (T_FUT * 2) + t * 2 + 0] = s0 + bout[0];
        out[(size_t)wave * (T_FUT * 2) + t * 2 + 1] = s1 + bout[1];
    }
}

extern "C" void kernel_launch(void* const* d_in, const int* in_sizes, int n_in,
                              void* d_out, int out_size, void* d_ws, size_t ws_size,
                              hipStream_t stream) {
    const float* history = (const float*)d_in[0];
    const float* eWih0 = (const float*)d_in[2];
    const float* eWhh0 = (const float*)d_in[3];
    const float* ebih0 = (const float*)d_in[4];
    const float* ebhh0 = (const float*)d_in[5];
    const float* eWih1 = (const float*)d_in[6];
    const float* eWhh1 = (const float*)d_in[7];
    const float* ebih1 = (const float*)d_in[8];
    const float* ebhh1 = (const float*)d_in[9];
    const float* dWih0 = (const float*)d_in[10];
    const float* dWhh0 = (const float*)d_in[11];
    const float* dbih0 = (const float*)d_in[12];
    const float* dbhh0 = (const float*)d_in[13];
    const float* dWih1 = (const float*)d_in[14];
    const float* dWhh1 = (const float*)d_in[15];
    const float* dbih1 = (const float*)d_in[16];
    const float* dbhh1 = (const float*)d_in[17];
    const float* outW  = (const float*)d_in[18];
    const float* outb  = (const float*)d_in[19];
    float* out = (float*)d_out;

    // ---- workspace layout ----
    const size_t M = (size_t)2048 * 512;
    ushort* whi = (ushort*)d_ws;           // 6 split-hi weight matrices
    ushort* wlo = whi + 6 * M;             // 6 split-lo
    ushort* hb  = wlo + 6 * M;             // 8 h buffers (hi/lo x 2 layers x dbuf)
    float*  c0  = (float*)(hb + 8 * M);
    float*  c1  = c0 + M;

    ushort* h0a_hi = hb + 0 * M; ushort* h0a_lo = hb + 1 * M;
    ushort* h0b_hi = hb + 2 * M; ushort* h0b_lo = hb + 3 * M;
    ushort* h1a_hi = hb + 4 * M; ushort* h1a_lo = hb + 5 * M;
    ushort* h1b_hi = hb + 6 * M; ushort* h1b_lo = hb + 7 * M;

    hipMemsetAsync(h0a_hi, 0, 2 * M * sizeof(ushort), stream);
    hipMemsetAsync(h1a_hi, 0, 2 * M * sizeof(ushort), stream);
    hipMemsetAsync(c0, 0, 2 * M * sizeof(float), stream);

    SplitSrc ss;
    ss.src[0] = eWhh0; ss.src[1] = eWih1; ss.src[2] = eWhh1;
    ss.src[3] = dWhh0; ss.src[4] = dWih1; ss.src[5] = dWhh1;
    split_weights<<<dim3(2048, 6), 256, 0, stream>>>(ss, whi, wlo);

    #define WHI(j) (whi + (size_t)(j) * M)
    #define WLO(j) (wlo + (size_t)(j) * M)

    auto H0R_HI = [&](int s){ return (s & 1) ? h0b_hi : h0a_hi; };
    auto H0R_LO = [&](int s){ return (s & 1) ? h0b_lo : h0a_lo; };
    auto H0W_HI = [&](int s){ return (s & 1) ? h0a_hi : h0b_hi; };
    auto H0W_LO = [&](int s){ return (s & 1) ? h0a_lo : h0b_lo; };
    auto H1R_HI = [&](int s){ return (s & 1) ? h1b_hi : h1a_hi; };
    auto H1R_LO = [&](int s){ return (s & 1) ? h1b_lo : h1a_lo; };
    auto H1W_HI = [&](int s){ return (s & 1) ? h1a_hi : h1b_hi; };
    auto H1W_LO = [&](int s){ return (s & 1) ? h1a_lo : h1b_lo; };

    auto mkL0enc = [&](int s) {
        CellDesc d{};
        d.A1h = H0R_HI(s); d.A1l = H0R_LO(s); d.W1h = WHI(0); d.W1l = WLO(0);
        d.np = 1; d.x = history + s * 5; d.xs = T_HIST * 5; d.Kx = 5; d.Wx = eWih0;
        d.bih = ebih0; d.bhh = ebhh0; d.c = c0; d.hh = H0W_HI(s); d.hl = H0W_LO(s);
        return d;
    };
    auto mkL1enc = [&](int s) {
        CellDesc d{};
        d.A1h = H0W_HI(s); d.A1l = H0W_LO(s); d.W1h = WHI(1); d.W1l = WLO(1);
        d.A2h = H1R_HI(s); d.A2l = H1R_LO(s); d.W2h = WHI(2); d.W2l = WLO(2);
        d.np = 2; d.Kx = 0; d.xs = 0;
        d.bih = ebih1; d.bhh = ebhh1; d.c = c1; d.hh = H1W_HI(s); d.hl = H1W_LO(s);
        return d;
    };
    // decoder layer-0: head folded in (x from h1(s-1)); s==T_HIST -> x=0
    auto mkD0 = [&](int s) {
        CellDesc d{};
        d.A1h = H0R_HI(s); d.A1l = H0R_LO(s); d.W1h = WHI(3); d.W1l = WLO(3);
        d.np = 1; d.Kx = 0; d.xs = 0; d.Wx = dWih0;
        if (s > T_HIST) {
            d.hsrc_hi = H1W_HI(s - 1); d.hsrc_lo = H1W_LO(s - 1);
            d.Wout = outW; d.bout = outb;
            d.out_t = out + (size_t)(s - T_HIST - 1) * 2;
        }
        d.bih = dbih0; d.bhh = dbhh0; d.c = c0; d.hh = H0W_HI(s); d.hl = H0W_LO(s);
        return d;
    };
    auto mkD1 = [&](int s) {
        CellDesc d{};
        d.A1h = H0W_HI(s); d.A1l = H0W_LO(s); d.W1h = WHI(4); d.W1l = WLO(4);
        d.A2h = H1R_HI(s); d.A2l = H1R_LO(s); d.W2h = WHI(5); d.W2l = WLO(5);
        d.np = 2; d.Kx = 0; d.xs = 0;
        d.bih = dbih1; d.bhh = dbhh1; d.c = c1; d.hh = H1W_HI(s); d.hl = H1W_LO(s);
        return d;
    };

    dim3 blk(256);

    // encoder step 0, layer 0 alone
    {
        CellDesc d = mkL0enc(0);
        lstm_cells<false><<<256, blk, 0, stream>>>(d, d);
    }
    // paired: [L1(s) || L0(s+1)]; last pair feeds the decoder (D0(50), x=0)
    for (int s = 0; s < T_HIST; ++s) {
        CellDesc dL1 = mkL1enc(s);
        CellDesc dNx = (s + 1 < T_HIST) ? mkL0enc(s + 1) : mkD0(T_HIST);
        lstm_cells<false><<<512, blk, 0, stream>>>(dL1, dNx);
    }
    // decoder: D1(s) -> D0(s+1) (head folded into D0's prologue, HF variant)
    for (int s = T_HIST; s < T_HIST + T_FUT; ++s) {
        CellDesc d1 = mkD1(s);
        lstm_cells<false><<<256, blk, 0, stream>>>(d1, d1);
        if (s + 1 < T_HIST + T_FUT) {
            CellDesc d0 = mkD0(s + 1);
            lstm_cells<true><<<256, blk, 0, stream>>>(d0, d0);
        }
    }
    // final prediction t = 29
    head_kernel<<<512, blk, 0, stream>>>(
        H1W_HI(T_HIST + T_FUT - 1), H1W_LO(T_HIST + T_FUT - 1),
        outW, outb, out, T_FUT - 1);
    #undef WHI
    #undef WLO
}